// Round 16
// baseline (1325.616 us; speedup 1.0000x reference)
//
#include <hip/hip_runtime.h>
#include <float.h>

#define NN 64000
#define BB 128
#define NPGc 500
#define EE 512000

// skew for LDS tiles: groups of 8 floats shifted by 4 floats -> distinct banks (r11 win)
#define SKW(c) ((c) + (((c)>>3)<<2))
#define LW 188

// ---------------- threefry2x32, JAX partitionable path, key = (0,42) ----------------
__device__ __forceinline__ unsigned rotl32(unsigned x, unsigned r){ return (x<<r)|(x>>(32u-r)); }

__device__ __forceinline__ unsigned threefry_bits(unsigned idx){
  unsigned x0 = 0u, x1 = idx;
  const unsigned ks0 = 0u, ks1 = 42u, ks2 = 0u ^ 42u ^ 0x1BD11BDAu;
  x0 += ks0; x1 += ks1;
#define RND(r) { x0 += x1; x1 = rotl32(x1, r); x1 ^= x0; }
  RND(13u) RND(15u) RND(26u) RND(6u)   x0 += ks1; x1 += ks2 + 1u;
  RND(17u) RND(29u) RND(16u) RND(24u)  x0 += ks2; x1 += ks0 + 2u;
  RND(13u) RND(15u) RND(26u) RND(6u)   x0 += ks0; x1 += ks1 + 3u;
  RND(17u) RND(29u) RND(16u) RND(24u)  x0 += ks1; x1 += ks2 + 4u;
  RND(13u) RND(15u) RND(26u) RND(6u)   x0 += ks2; x1 += ks0 + 5u;
#undef RND
  return x0 ^ x1;
}

__device__ __forceinline__ float gumbel_of(unsigned idx){
  unsigned bits = threefry_bits(idx);
  float f = __uint_as_float((bits >> 9) | 0x3f800000u) - 1.0f;
  const float TINY = 1.17549435e-38f;
  float u = fmaxf(TINY, f + TINY);
  return -logf(-logf(u));   // precise logf: argmax must match ref bit-wise
}

__device__ __forceinline__ float fast_tanh(float x){
  return 1.0f - 2.0f/(__expf(2.0f*x) + 1.0f);
}

// ---------------- uchar masks (vectorized, self-detecting dtype) ----------------
__global__ __launch_bounds__(256)
void maskprep_kernel(const unsigned char* __restrict__ mu8src, const int* __restrict__ mi32src,
                     unsigned char* __restrict__ mn8, unsigned char* __restrict__ mt8){
  __shared__ unsigned char tile[64][65];
  const int b = blockIdx.y;
  const int rt = blockIdx.x >> 3, ct = blockIdx.x & 7;
  const int t = threadIdx.x;
  int mybad = (((const unsigned*)mi32src)[t] > 1u) ? 1 : 0;
  int isbool = __syncthreads_or(mybad);
  const int rl = t >> 4;          // 0..15
  const int cq = t & 15;          // col quad
#pragma unroll
  for (int p=0;p<4;p++){
    int row = rt*64 + p*16 + rl;
    int col = ct*64 + cq*4;
    uchar4 v; v.x=0; v.y=0; v.z=0; v.w=0;
    if (row < NPGc && col < NPGc){
      size_t o = (size_t)b*250000 + (size_t)row*500 + col;
      if (isbool){
        v = *(const uchar4*)(mu8src + o);
      } else {
        int4 w = *(const int4*)(mi32src + o);
        v.x = (unsigned char)(w.x!=0); v.y = (unsigned char)(w.y!=0);
        v.z = (unsigned char)(w.z!=0); v.w = (unsigned char)(w.w!=0);
      }
      *(uchar4*)(mn8 + o) = v;
    }
    int lr = p*16 + rl, lc = cq*4;
    tile[lr][lc+0]=v.x; tile[lr][lc+1]=v.y; tile[lr][lc+2]=v.z; tile[lr][lc+3]=v.w;
  }
  __syncthreads();
#pragma unroll
  for (int p=0;p<4;p++){
    int orow = ct*64 + p*16 + rl;
    int ocol = rt*64 + cq*4;
    if (orow < NPGc && ocol < NPGc){
      uchar4 v;
      v.x = tile[cq*4+0][p*16+rl];
      v.y = tile[cq*4+1][p*16+rl];
      v.z = tile[cq*4+2][p*16+rl];
      v.w = tile[cq*4+3][p*16+rl];
      *(uchar4*)(mt8 + (size_t)b*250000 + (size_t)orow*500 + ocol) = v;
    }
  }
}

// ---------------- CSR build ----------------
__global__ void count_kernel(const int* __restrict__ dst, int* __restrict__ cnt){
  int e = blockIdx.x*256 + threadIdx.x;
  if (e < EE) atomicAdd(&cnt[dst[e]], 1);
}

__global__ void scanA_kernel(const int* __restrict__ cnt, int* __restrict__ bsum){
  __shared__ int red[256];
  int t = threadIdx.x;
  red[t] = cnt[blockIdx.x*256 + t];
  __syncthreads();
  for (int s=128;s>0;s>>=1){
    if (t < s) red[t] += red[t+s];
    __syncthreads();
  }
  if (t == 0) bsum[blockIdx.x] = red[0];
}

__global__ void scanB_kernel(const int* __restrict__ bsum, int* __restrict__ boff){
  __shared__ int red[256];
  int t = threadIdx.x;
  int v = (t < 250) ? bsum[t] : 0;
  red[t] = v;
  __syncthreads();
  for (int d=1; d<256; d<<=1){
    int x = (t >= d) ? red[t-d] : 0;
    __syncthreads();
    red[t] += x;
    __syncthreads();
  }
  if (t < 250) boff[t] = red[t] - v;
  if (t == 249) boff[250] = red[t];
}

__global__ void scanC_kernel(const int* __restrict__ cnt, const int* __restrict__ boff,
                             int* __restrict__ off, int* __restrict__ cur){
  __shared__ int red[256];
  int t = threadIdx.x;
  int n = blockIdx.x*256 + t;
  int v = cnt[n];
  red[t] = v;
  __syncthreads();
  for (int d=1; d<256; d<<=1){
    int x = (t >= d) ? red[t-d] : 0;
    __syncthreads();
    red[t] += x;
    __syncthreads();
  }
  int excl = red[t] - v + boff[blockIdx.x];
  off[n] = excl; cur[n] = excl;
  if (n == NN-1) off[NN] = excl + v;
}

__global__ void fill_kernel(const int* __restrict__ src, const int* __restrict__ dst,
                            int* __restrict__ cur, int* __restrict__ csr){
  int e = blockIdx.x*256 + threadIdx.x;
  if (e < EE){
    int d = dst[e];
    int p = atomicAdd(&cur[d], 1);
    csr[p] = src[e];
  }
}

// ---------------- aggregation (layer >=1): big-grid standalone (TLP hides miss latency) ----
__global__ __launch_bounds__(256)
void agg128_kernel(const float* __restrict__ h, const int* __restrict__ off,
                   const int* __restrict__ csr, const int* __restrict__ cnt,
                   float* __restrict__ xin){
  const int nb = gridDim.x;
  const int per = nb >> 3;
  int bid = (blockIdx.x % 8)*per + (blockIdx.x >> 3);
  int w = (bid*256 + (int)threadIdx.x) >> 6;
  int lane = threadIdx.x & 63;
  if (w >= NN) return;
  const float* hn = h + (size_t)w*128;
  float a0 = hn[lane], a1 = hn[lane+64];
  float s0 = a0, s1 = a1;
  int e0 = off[w], e1 = off[w+1];
  int e = e0;
  for (; e + 4 <= e1; e += 4){
    int sA = csr[e], sB = csr[e+1], sC = csr[e+2], sD = csr[e+3];
    const float* pA = h + (size_t)sA*128;
    const float* pB = h + (size_t)sB*128;
    const float* pC = h + (size_t)sC*128;
    const float* pD = h + (size_t)sD*128;
    float a0A = pA[lane], a1A = pA[lane+64];
    float a0B = pB[lane], a1B = pB[lane+64];
    float a0C = pC[lane], a1C = pC[lane+64];
    float a0D = pD[lane], a1D = pD[lane+64];
    s0 += a0A; s1 += a1A;
    s0 += a0B; s1 += a1B;
    s0 += a0C; s1 += a1C;
    s0 += a0D; s1 += a1D;
  }
  for (; e < e1; ++e){
    int s = csr[e];
    const float* hs = h + (size_t)s*128;
    s0 += hs[lane]; s1 += hs[lane+64];
  }
  float di = 1.0f/(float)(cnt[w]+1);
  xin[(size_t)w*128 + lane]      = a0 + s0*di;
  xin[(size_t)w*128 + lane + 64] = a1 + s1*di;
}

// ---------------- layer-0: fused agg3 + z (K=3) with BN stats ----------------
__global__ __launch_bounds__(256)
void z0_kernel(const float* __restrict__ x, const int* __restrict__ off,
               const int* __restrict__ csr, const int* __restrict__ cnt,
               const float* __restrict__ W, const float* __restrict__ bias,
               float* __restrict__ z, float* __restrict__ stats){
  __shared__ float xr[192];
  __shared__ float ssum[128], ssq[128];
  int t = threadIdx.x;
  int row0 = blockIdx.x*64;
  if (t < 192){
    int nl = t/3, f = t - nl*3;
    int n = row0 + nl;
    float a = x[n*3+f];
    float s = a;
    int e1 = off[n+1];
    for (int e = off[n]; e < e1; ++e) s += x[csr[e]*3 + f];
    float di = 1.0f/(float)(cnt[n]+1);
    xr[t] = a + s*di;
  }
  if (t < 128){ ssum[t]=0.f; ssq[t]=0.f; }
  int f = t & 127, rg = t >> 7;
  float w0 = W[f], w1 = W[128+f], w2 = W[256+f], bb = bias[f];
  __syncthreads();
  float s = 0.f, q = 0.f;
  for (int i=0;i<32;i++){
    int r = rg*32 + i;
    float y = bb + xr[r*3]*w0 + xr[r*3+1]*w1 + xr[r*3+2]*w2;
    z[(size_t)(row0+r)*128 + f] = y;
    s += y; q += y*y;
  }
  atomicAdd(&ssum[f], s); atomicAdd(&ssq[f], q);
  __syncthreads();
  if (t < 128){ atomicAdd(&stats[t], ssum[t]); atomicAdd(&stats[128+t], ssq[t]); }
}

// ---------------- fp32 linear: 128 rows x 128 out per block, 8x8 micro-tile ----------------
// BN finalize folded into prologue. Do NOT grow the accumulator (16x8 spills: r8).
// Do NOT tighten bounds ((256,4) spills: r5).
template<int K, bool CATF, bool BNF, bool TANHF, bool STATSF, int POOLM>
__global__ __launch_bounds__(256, 2)
void linear_kernel(const float* X, const float* __restrict__ X2,
                   const float* __restrict__ W, const float* __restrict__ bias,
                   float* Y,
                   const float* __restrict__ statsIn, const float* __restrict__ gam,
                   const float* __restrict__ bet,
                   float* __restrict__ statsOut, float* __restrict__ pool){
  __shared__ __align__(16) float xs[32][LW];
  __shared__ __align__(16) float ws[32][LW];
  __shared__ float ssum[128], ssq[128];
  __shared__ __align__(16) float bnsc_s[128], bnsh_s[128];
  const int t = threadIdx.x;
  const int row0 = blockIdx.x*128;
  const int cg = t & 15, rg = t >> 4;
  const int c0 = cg*8, r0 = rg*8;
  const int skr0 = SKW(r0), skc0 = SKW(c0);
  float acc[8][8];
#pragma unroll
  for (int r=0;r<8;r++)
#pragma unroll
    for (int c=0;c<8;c++) acc[r][c]=0.f;
  if (STATSF && t < 128){ ssum[t]=0.f; ssq[t]=0.f; }
  if (BNF && t < 128){
    float mu  = statsIn[t]     * (1.0f/NN);
    float var = statsIn[128+t] * (1.0f/NN) - mu*mu;
    float rsv = rsqrtf(var + 1e-5f);
    float sc  = gam[t]*rsv;
    bnsc_s[t] = sc;
    bnsh_s[t] = bet[t] - mu*sc;
  }

  for (int kc=0; kc<K; kc+=32){
    __syncthreads();
#pragma unroll
    for (int i=0;i<4;i++){
      int task = t + 256*i;
      int n = task >> 3, k4 = task & 7;
      int gk = kc + k4*4;
      int row = row0 + n;
      float4 v;
      if (CATF){
        if (gk < 128) v = *(const float4*)(X  + (size_t)row*128 + gk);
        else          v = *(const float4*)(X2 + (size_t)(row/NPGc)*128 + (gk-128));
      } else {
        v = *(const float4*)(X + (size_t)row*K + gk);
      }
      if (BNF){
        float4 sc4 = *(const float4*)(bnsc_s + gk);
        float4 sh4 = *(const float4*)(bnsh_s + gk);
        v.x = fmaxf(0.f, v.x*sc4.x + sh4.x);
        v.y = fmaxf(0.f, v.y*sc4.y + sh4.y);
        v.z = fmaxf(0.f, v.z*sc4.z + sh4.z);
        v.w = fmaxf(0.f, v.w*sc4.w + sh4.w);
      }
      int ns = SKW(n);
      xs[k4*4+0][ns] = v.x; xs[k4*4+1][ns] = v.y;
      xs[k4*4+2][ns] = v.z; xs[k4*4+3][ns] = v.w;
    }
#pragma unroll
    for (int i=0;i<4;i++){
      int task = t + 256*i;
      int k = task >> 5, c4 = task & 31;
      float4 v = *(const float4*)(W + (size_t)(kc+k)*128 + c4*4);
      *(float4*)&ws[k][c4*4 + ((c4>>1)<<2)] = v;
    }
    __syncthreads();
#pragma unroll
    for (int k=0;k<32;k++){
      float4 xa = *(const float4*)&xs[k][skr0];
      float4 xb = *(const float4*)&xs[k][skr0+4];
      float4 wa = *(const float4*)&ws[k][skc0];
      float4 wb = *(const float4*)&ws[k][skc0+4];
      float xv[8] = {xa.x,xa.y,xa.z,xa.w,xb.x,xb.y,xb.z,xb.w};
      float wv[8] = {wa.x,wa.y,wa.z,wa.w,wb.x,wb.y,wb.z,wb.w};
#pragma unroll
      for (int r=0;r<8;r++)
#pragma unroll
        for (int c=0;c<8;c++)
          acc[r][c] += xv[r]*wv[c];
    }
  }
  float4 ba = *(const float4*)(bias + c0);
  float4 bb2 = *(const float4*)(bias + c0 + 4);
  float bv[8] = {ba.x,ba.y,ba.z,ba.w,bb2.x,bb2.y,bb2.z,bb2.w};
  float sc8[8], sq8[8];
#pragma unroll
  for (int c=0;c<8;c++){ sc8[c]=0.f; sq8[c]=0.f; }
#pragma unroll
  for (int r=0;r<8;r++){
    int n = row0 + r0 + r;
    float y[8];
#pragma unroll
    for (int c=0;c<8;c++){
      float v = acc[r][c] + bv[c];
      if (TANHF) v = fast_tanh(v);
      y[c] = v;
    }
    float4 y0; y0.x=y[0]; y0.y=y[1]; y0.z=y[2]; y0.w=y[3];
    float4 y1; y1.x=y[4]; y1.y=y[5]; y1.z=y[6]; y1.w=y[7];
    *(float4*)(Y + (size_t)n*128 + c0)     = y0;
    *(float4*)(Y + (size_t)n*128 + c0 + 4) = y1;
    if (POOLM == 1){
      *(float4*)(pool + (size_t)n*128 + c0)     = y0;
      *(float4*)(pool + (size_t)n*128 + c0 + 4) = y1;
    } else if (POOLM == 2){
      float4 p0 = *(const float4*)(pool + (size_t)n*128 + c0);
      float4 p1 = *(const float4*)(pool + (size_t)n*128 + c0 + 4);
      p0.x+=y[0]; p0.y+=y[1]; p0.z+=y[2]; p0.w+=y[3];
      p1.x+=y[4]; p1.y+=y[5]; p1.z+=y[6]; p1.w+=y[7];
      *(float4*)(pool + (size_t)n*128 + c0)     = p0;
      *(float4*)(pool + (size_t)n*128 + c0 + 4) = p1;
    }
    if (STATSF){
#pragma unroll
      for (int c=0;c<8;c++){ sc8[c]+=y[c]; sq8[c]+=y[c]*y[c]; }
    }
  }
  if (STATSF){
#pragma unroll
    for (int c=0;c<8;c++){
      atomicAdd(&ssum[c0+c], sc8[c]);
      atomicAdd(&ssq[c0+c],  sq8[c]);
    }
    __syncthreads();
    if (t < 128){
      atomicAdd(&statsOut[t],     ssum[t]);
      atomicAdd(&statsOut[128+t], ssq[t]);
    }
  }
}

// ---------------- graph pool (mean of node_pool per graph), 4-way row-parallel ----------------
__global__ __launch_bounds__(512)
void gpool_kernel(const float* __restrict__ pool, float* __restrict__ gpool){
  __shared__ float red[4][128];
  int b = blockIdx.x;
  int f = threadIdx.x & 127, part = threadIdx.x >> 7;
  const float* p = pool + (size_t)b*NPGc*128 + f;
  int rbeg = part*125, rend = rbeg + 125;
  float s = 0.f;
  for (int i=rbeg;i<rend;i++) s += p[(size_t)i*128];
  red[part][f] = s;
  __syncthreads();
  if (part == 0){
    float tot = ((red[0][f] + red[1][f]) + red[2][f]) + red[3][f];
    gpool[(size_t)b*128 + f] = tot * (1.0f/NPGc);
  }
}

// ---------------- triangle scores, 128x128 tile pairs, 8x8 micro-tile ----------------
// 4 tiles of 128 rows -> 10 pairs (tn<=tm) per graph; 1280 blocks XCD-pinned.
// GEMM: both operands staged [k][SKW(row)] per 32-k chunk (linear_kernel's proven tiling):
// 4 b128 per 64 FMA = half the LDS traffic of the old 64x64/4x4 version (92us LDS floor -> 51).
// Per-element k order unchanged (kc asc x kk asc) -> scores bit-identical -> argmax bit-stable.
// Tail: 8 row-phases, queue drain per phase (expected ~410 pushes/phase << QCAP).
#define QCAP 1024
#define NPAIR 10

__global__ __launch_bounds__(256)
void scores_tri_kernel(const float* __restrict__ A, const unsigned char* __restrict__ mn8,
                       const unsigned char* __restrict__ mt8, float* __restrict__ partials){
  __shared__ __align__(16) float as[32][LW];
  __shared__ __align__(16) float bs[32][LW];
  __shared__ float qs[QCAP];
  __shared__ int   qi[QCAP];
  __shared__ int   qcnt;
  float* rm  = qs;
  float* rs_ = qs + 256;
  float* rv  = qs + 512;
  float* rsc = qs + 768;
  int*   ri  = qi;
  const int t = threadIdx.x;
  const int xcd = blockIdx.x & 7;            // 1280 = 8 x 160
  const int within = blockIdx.x >> 3;        // 0..159
  const int b = xcd*16 + within/NPAIR;
  const int pair = within % NPAIR;
  int pidx = pair, tn = 0;
  while (pidx >= 4 - tn){ pidx -= 4 - tn; tn++; }
  const int tm = tn + pidx;
  const bool diag = (tn == tm);
  const int n0 = tn*128, m0 = tm*128;
  const int cg = t & 15, rg = t >> 4;
  const int c0 = cg*8, r0 = rg*8;
  const int skr0 = SKW(r0), skc0 = SKW(c0);
  const float* Ab = A + (size_t)b*NPGc*128;
  const unsigned gbase = (unsigned)b*250000u;
  if (t == 0) qcnt = 0;

  float acc[8][8];
#pragma unroll
  for (int r=0;r<8;r++)
#pragma unroll
    for (int c=0;c<8;c++) acc[r][c]=0.f;

  for (int kc=0; kc<128; kc+=32){
    __syncthreads();
    // stage as: 1024 tasks (128 n-rows x 8 k-quads)
#pragma unroll
    for (int i=0;i<4;i++){
      int task = t + 256*i;
      int n = task >> 3, k4 = task & 7;
      int gk = kc + k4*4;
      int gn = n0 + n;
      float4 v;
      if (gn < NPGc) v = *(const float4*)(Ab + (size_t)gn*128 + gk);
      else { v.x=0.f; v.y=0.f; v.z=0.f; v.w=0.f; }
      int ns = SKW(n);
      as[k4*4+0][ns] = v.x; as[k4*4+1][ns] = v.y;
      as[k4*4+2][ns] = v.z; as[k4*4+3][ns] = v.w;
    }
    // stage bs: m-rows
#pragma unroll
    for (int i=0;i<4;i++){
      int task = t + 256*i;
      int m = task >> 3, k4 = task & 7;
      int gk = kc + k4*4;
      int gm = m0 + m;
      float4 v;
      if (gm < NPGc) v = *(const float4*)(Ab + (size_t)gm*128 + gk);
      else { v.x=0.f; v.y=0.f; v.z=0.f; v.w=0.f; }
      int ms = SKW(m);
      bs[k4*4+0][ms] = v.x; bs[k4*4+1][ms] = v.y;
      bs[k4*4+2][ms] = v.z; bs[k4*4+3][ms] = v.w;
    }
    __syncthreads();
#pragma unroll
    for (int k=0;k<32;k++){
      float4 xa = *(const float4*)&as[k][skr0];
      float4 xb = *(const float4*)&as[k][skr0+4];
      float4 wa = *(const float4*)&bs[k][skc0];
      float4 wb = *(const float4*)&bs[k][skc0+4];
      float xv[8] = {xa.x,xa.y,xa.z,xa.w,xb.x,xb.y,xb.z,xb.w};
      float wv[8] = {wa.x,wa.y,wa.z,wa.w,wb.x,wb.y,wb.z,wb.w};
#pragma unroll
      for (int r=0;r<8;r++)
#pragma unroll
        for (int c=0;c<8;c++)
          acc[r][c] += xv[r]*wv[c];
    }
  }

  // ---- tail: mask + online softmax + gumbel argmax; 8 row-phases with drains ----
  float mrun = -1e30f, srun = 0.f, bval = -FLT_MAX, bsc = 0.f;
  int bidx = 0x7FFFFFFF;
  const int mbase = m0 + c0;
  // barrier before first aliased-queue use is the one after GEMM's last stage; qcnt was set
  // before any __syncthreads-protected region ended, and no queue writes happened yet.
  __syncthreads();
#pragma unroll
  for (int r=0;r<8;r++){
    int n = n0 + r0 + r;
    bool rowok = (n < NPGc) && (mbase < NPGc);
    bool fn[8] = {false,false,false,false,false,false,false,false};
    bool fm[8] = {false,false,false,false,false,false,false,false};
    if (rowok){
      size_t moff = (size_t)b*250000 + (size_t)n*500 + (size_t)mbase;
      uchar4 k0 = *(const uchar4*)(mn8 + moff);
      uchar4 k1 = *(const uchar4*)(mn8 + moff + 4);
      fn[0]=k0.x!=0; fn[1]=k0.y!=0; fn[2]=k0.z!=0; fn[3]=k0.w!=0;
      fn[4]=k1.x!=0; fn[5]=k1.y!=0; fn[6]=k1.z!=0; fn[7]=k1.w!=0;
      uchar4 t0 = *(const uchar4*)(mt8 + moff);
      uchar4 t1 = *(const uchar4*)(mt8 + moff + 4);
      fm[0]=t0.x!=0; fm[1]=t0.y!=0; fm[2]=t0.z!=0; fm[3]=t0.w!=0;
      fm[4]=t1.x!=0; fm[5]=t1.y!=0; fm[6]=t1.z!=0; fm[7]=t1.w!=0;
    }
    float cntj[8], sj[8];
    bool pn[8], pm[8];
#pragma unroll
    for (int j=0;j<8;j++){
      int m = mbase + j;
      bool mok = rowok && (m < NPGc);
      bool keep = mok && (!diag || m >= n);
      bool isde = (n == m);
      float cnt = 0.f; bool a1=false, a2=false;
      if (keep){
        if (isde){ cnt = fn[j] ? 1.f : 0.f; a1 = fn[j]; }
        else { cnt = (fn[j]?1.f:0.f) + (fm[j]?1.f:0.f); a1 = fn[j]; a2 = fm[j]; }
      }
      cntj[j]=cnt; pn[j]=a1; pm[j]=a2;
      sj[j] = (cnt > 0.f) ? acc[r][j] : -1e30f;
    }
    float tmx = sj[0];
#pragma unroll
    for (int j=1;j<8;j++) tmx = fmaxf(tmx, sj[j]);
    float nm = fmaxf(mrun, tmx);
    float add = 0.f;
#pragma unroll
    for (int j=0;j<8;j++) add += cntj[j]*__expf(sj[j] - nm);
    srun = srun*__expf(mrun - nm) + add;
    mrun = nm;
#pragma unroll
    for (int j=0;j<8;j++){
      int m = mbase + j;
      if (pn[j] || pm[j]){
        float s = acc[r][j];
#pragma unroll
        for (int d=0;d<2;d++){
          bool doit = d ? pm[j] : pn[j];
          if (doit){
            int lidx = d ? (m*500 + n) : (n*500 + m);
            int slot = atomicAdd(&qcnt, 1);
            if (slot < QCAP){ qs[slot] = s; qi[slot] = lidx; }
            else {
              float g = gumbel_of(gbase + (unsigned)lidx);
              float val = s + g;
              if (val > bval || (val == bval && lidx < bidx)){ bval = val; bidx = lidx; bsc = s; }
            }
          }
        }
      }
    }
    // drain this phase
    __syncthreads();
    int qn = qcnt; if (qn > QCAP) qn = QCAP;
    for (int i = t; i < qn; i += 256){
      float s = qs[i]; int idx = qi[i];
      float g = gumbel_of(gbase + (unsigned)idx);
      float val = s + g;
      if (val > bval || (val == bval && idx < bidx)){ bval = val; bidx = idx; bsc = s; }
    }
    __syncthreads();
    if (t == 0) qcnt = 0;
    __syncthreads();
  }
  rm[t]=mrun; rs_[t]=srun; rv[t]=bval; ri[t]=bidx; rsc[t]=bsc;
  __syncthreads();
  for (int offr=128; offr>0; offr>>=1){
    if (t < offr){
      float m1 = rm[t], s1 = rs_[t];
      float m2 = rm[t+offr], s2 = rs_[t+offr];
      float M = fmaxf(m1, m2);
      float S = s1*expf(m1-M) + s2*expf(m2-M);
      rm[t] = M; rs_[t] = S;
      float v2 = rv[t+offr]; int i2_ = ri[t+offr];
      if (v2 > rv[t] || (v2 == rv[t] && i2_ < ri[t])){ rv[t]=v2; ri[t]=i2_; rsc[t]=rsc[t+offr]; }
    }
    __syncthreads();
  }
  if (t == 0){
    float* p = partials + ((size_t)b*NPAIR + pair)*8;
    p[0]=rm[0]; p[1]=rs_[0]; p[2]=rv[0]; p[3]=(float)ri[0]; p[4]=rsc[0];
  }
}

__global__ void finalize_kernel(const float* __restrict__ partials, float* __restrict__ out){
  int b = threadIdx.x;
  float M = -1e30f, S = 0.f, BV = -FLT_MAX, BS = 0.f;
  int BI = 0x7FFFFFFF;
  for (int tp=0; tp<NPAIR; tp++){
    const float* p = partials + ((size_t)b*NPAIR + tp)*8;
    float m = p[0], s = p[1], v = p[2]; int i = (int)p[3]; float sc2 = p[4];
    float nM = fmaxf(M, m);
    S = S*expf(M-nM) + s*expf(m-nM);
    M = nM;
    if (v > BV || (v == BV && i < BI)){ BV = v; BI = i; BS = sc2; }
  }
  out[b]      = (float)BI;
  out[BB + b] = BS - (M + logf(S));
}

// ---------------- host launch ----------------
extern "C" void kernel_launch(void* const* d_in, const int* in_sizes, int n_in,
                              void* d_out, int out_size, void* d_ws, size_t ws_size,
                              hipStream_t stream){
  const float* x        = (const float*)d_in[0];
  const int*   eidx     = (const int*)d_in[1];
  const void*  maskp    = d_in[3];
  const float* gin_W1_0 = (const float*)d_in[4];
  const float* gin_b1_0 = (const float*)d_in[5];
  const float* gin_g_0  = (const float*)d_in[6];
  const float* gin_be_0 = (const float*)d_in[7];
  const float* gin_W2_0 = (const float*)d_in[8];
  const float* gin_b2_0 = (const float*)d_in[9];
  const float* gin_W1   = (const float*)d_in[10];
  const float* gin_b1   = (const float*)d_in[11];
  const float* gin_g    = (const float*)d_in[12];
  const float* gin_be   = (const float*)d_in[13];
  const float* gin_W2   = (const float*)d_in[14];
  const float* gin_b2   = (const float*)d_in[15];
  const float* pol_W1_0 = (const float*)d_in[16];
  const float* pol_b1_0 = (const float*)d_in[17];
  const float* pol_W2_0 = (const float*)d_in[18];
  const float* pol_b2_0 = (const float*)d_in[19];
  const float* pol_W1   = (const float*)d_in[20];
  const float* pol_b1   = (const float*)d_in[21];
  const float* pol_W2   = (const float*)d_in[22];
  const float* pol_b2   = (const float*)d_in[23];
  float* out = (float*)d_out;

  char* p = (char*)d_ws;
  auto carve = [&](size_t bytes) -> void* {
    void* r = (void*)p; p += (bytes + 255) & ~(size_t)255; return r;
  };
  float* hbuf  = (float*)carve((size_t)NN*128*4);
  float* xin   = (float*)carve((size_t)NN*128*4);
  float* pool  = (float*)carve((size_t)NN*128*4);
  float* gpool = (float*)carve((size_t)BB*128*4);
  float* stats = (float*)carve(4*256*4);
  float* partials = (float*)carve((size_t)BB*NPAIR*8*4);
  int* cnt  = (int*)carve((size_t)NN*4);
  int* off  = (int*)carve((size_t)(NN+1)*4);
  int* cur  = (int*)carve((size_t)NN*4);
  int* csr  = (int*)carve((size_t)EE*4);
  int* bsum = (int*)carve(256*4);
  int* boff = (int*)carve(256*4);
  unsigned char* mn8 = (unsigned char*)carve((size_t)BB*250000);
  unsigned char* mt8 = (unsigned char*)carve((size_t)BB*250000);

  const int* srcp = eidx;
  const int* dstp = eidx + EE;

  {
    dim3 mg(64, BB);
    maskprep_kernel<<<mg, 256, 0, stream>>>((const unsigned char*)maskp, (const int*)maskp,
                                            mn8, mt8);
  }

  hipMemsetAsync(cnt, 0, (size_t)NN*4, stream);
  hipMemsetAsync(stats, 0, 4*256*4, stream);
  count_kernel<<<(EE+255)/256, 256, 0, stream>>>(dstp, cnt);
  scanA_kernel<<<NN/256, 256, 0, stream>>>(cnt, bsum);
  scanB_kernel<<<1, 256, 0, stream>>>(bsum, boff);
  scanC_kernel<<<NN/256, 256, 0, stream>>>(cnt, boff, off, cur);
  fill_kernel<<<(EE+255)/256, 256, 0, stream>>>(srcp, dstp, cur, csr);

  // GIN layer 0
  z0_kernel<<<NN/64, 256, 0, stream>>>(x, off, csr, cnt, gin_W1_0, gin_b1_0, xin, stats);
  linear_kernel<128,false,true,false,false,1><<<NN/128, 256, 0, stream>>>(
      xin, nullptr, gin_W2_0, gin_b2_0, hbuf, stats, gin_g_0, gin_be_0, nullptr, pool);

  // GIN layers 1..3
  for (int l=0; l<3; l++){
    float* st = stats + (l+1)*256;
    agg128_kernel<<<NN/4, 256, 0, stream>>>(hbuf, off, csr, cnt, xin);
    linear_kernel<128,false,false,false,true,0><<<NN/128, 256, 0, stream>>>(
        xin, nullptr, gin_W1 + (size_t)l*16384, gin_b1 + l*128, xin,
        nullptr, nullptr, nullptr, st, nullptr);
    linear_kernel<128,false,true,false,false,2><<<NN/128, 256, 0, stream>>>(
        xin, nullptr, gin_W2 + (size_t)l*16384, gin_b2 + l*128, hbuf,
        st, gin_g + l*128, gin_be + l*128, nullptr, pool);
  }

  // policy MLP
  gpool_kernel<<<BB, 512, 0, stream>>>(pool, gpool);
  linear_kernel<256,true,false,true,false,0><<<NN/128, 256, 0, stream>>>(
      pool, gpool, pol_W1_0, pol_b1_0, hbuf, nullptr, nullptr, nullptr, nullptr, nullptr);
  linear_kernel<128,false,false,false,false,0><<<NN/128, 256, 0, stream>>>(
      hbuf, nullptr, pol_W2_0, pol_b2_0, xin, nullptr, nullptr, nullptr, nullptr, nullptr);
  linear_kernel<128,false,false,true,false,0><<<NN/128, 256, 0, stream>>>(
      xin, nullptr, pol_W1, pol_b1, hbuf, nullptr, nullptr, nullptr, nullptr, nullptr);
  linear_kernel<128,false,false,false,false,0><<<NN/128, 256, 0, stream>>>(
      hbuf, nullptr, pol_W2, pol_b2, xin, nullptr, nullptr, nullptr, nullptr, nullptr);
  linear_kernel<128,false,false,true,false,0><<<NN/128, 256, 0, stream>>>(
      xin, nullptr, pol_W1 + 16384, pol_b1 + 128, hbuf, nullptr, nullptr, nullptr, nullptr, nullptr);
  linear_kernel<128,false,false,false,false,0><<<NN/128, 256, 0, stream>>>(
      hbuf, nullptr, pol_W2 + 16384, pol_b2 + 128, xin, nullptr, nullptr, nullptr, nullptr, nullptr);

  // scores + sampling (128x128 tile pairs, XCD-pinned)
  scores_tri_kernel<<<8*16*NPAIR, 256, 0, stream>>>(xin, mn8, mt8, partials);
  finalize_kernel<<<1, BB, 0, stream>>>(partials, out);
}

// Round 17
// 1174.032 us; speedup vs baseline: 1.1291x; 1.1291x over previous
//
#include <hip/hip_runtime.h>
#include <float.h>

#define NN 64000
#define BB 128
#define NPGc 500
#define EE 512000

// skew for LDS tiles: groups of 8 floats shifted by 4 floats -> distinct banks (r11 win)
#define SKW(c) ((c) + (((c)>>3)<<2))
#define LW 188

// ---------------- threefry2x32, JAX partitionable path, key = (0,42) ----------------
__device__ __forceinline__ unsigned rotl32(unsigned x, unsigned r){ return (x<<r)|(x>>(32u-r)); }

__device__ __forceinline__ unsigned threefry_bits(unsigned idx){
  unsigned x0 = 0u, x1 = idx;
  const unsigned ks0 = 0u, ks1 = 42u, ks2 = 0u ^ 42u ^ 0x1BD11BDAu;
  x0 += ks0; x1 += ks1;
#define RND(r) { x0 += x1; x1 = rotl32(x1, r); x1 ^= x0; }
  RND(13u) RND(15u) RND(26u) RND(6u)   x0 += ks1; x1 += ks2 + 1u;
  RND(17u) RND(29u) RND(16u) RND(24u)  x0 += ks2; x1 += ks0 + 2u;
  RND(13u) RND(15u) RND(26u) RND(6u)   x0 += ks0; x1 += ks1 + 3u;
  RND(17u) RND(29u) RND(16u) RND(24u)  x0 += ks1; x1 += ks2 + 4u;
  RND(13u) RND(15u) RND(26u) RND(6u)   x0 += ks2; x1 += ks0 + 5u;
#undef RND
  return x0 ^ x1;
}

__device__ __forceinline__ float gumbel_of(unsigned idx){
  unsigned bits = threefry_bits(idx);
  float f = __uint_as_float((bits >> 9) | 0x3f800000u) - 1.0f;
  const float TINY = 1.17549435e-38f;
  float u = fmaxf(TINY, f + TINY);
  return -logf(-logf(u));   // precise logf: argmax must match ref bit-wise
}

__device__ __forceinline__ float fast_tanh(float x){
  return 1.0f - 2.0f/(__expf(2.0f*x) + 1.0f);
}

// ---------------- uchar masks (vectorized, self-detecting dtype) ----------------
__global__ __launch_bounds__(256)
void maskprep_kernel(const unsigned char* __restrict__ mu8src, const int* __restrict__ mi32src,
                     unsigned char* __restrict__ mn8, unsigned char* __restrict__ mt8){
  __shared__ unsigned char tile[64][65];
  const int b = blockIdx.y;
  const int rt = blockIdx.x >> 3, ct = blockIdx.x & 7;
  const int t = threadIdx.x;
  int mybad = (((const unsigned*)mi32src)[t] > 1u) ? 1 : 0;
  int isbool = __syncthreads_or(mybad);
  const int rl = t >> 4;          // 0..15
  const int cq = t & 15;          // col quad
#pragma unroll
  for (int p=0;p<4;p++){
    int row = rt*64 + p*16 + rl;
    int col = ct*64 + cq*4;
    uchar4 v; v.x=0; v.y=0; v.z=0; v.w=0;
    if (row < NPGc && col < NPGc){
      size_t o = (size_t)b*250000 + (size_t)row*500 + col;
      if (isbool){
        v = *(const uchar4*)(mu8src + o);
      } else {
        int4 w = *(const int4*)(mi32src + o);
        v.x = (unsigned char)(w.x!=0); v.y = (unsigned char)(w.y!=0);
        v.z = (unsigned char)(w.z!=0); v.w = (unsigned char)(w.w!=0);
      }
      *(uchar4*)(mn8 + o) = v;
    }
    int lr = p*16 + rl, lc = cq*4;
    tile[lr][lc+0]=v.x; tile[lr][lc+1]=v.y; tile[lr][lc+2]=v.z; tile[lr][lc+3]=v.w;
  }
  __syncthreads();
#pragma unroll
  for (int p=0;p<4;p++){
    int orow = ct*64 + p*16 + rl;
    int ocol = rt*64 + cq*4;
    if (orow < NPGc && ocol < NPGc){
      uchar4 v;
      v.x = tile[cq*4+0][p*16+rl];
      v.y = tile[cq*4+1][p*16+rl];
      v.z = tile[cq*4+2][p*16+rl];
      v.w = tile[cq*4+3][p*16+rl];
      *(uchar4*)(mt8 + (size_t)b*250000 + (size_t)orow*500 + ocol) = v;
    }
  }
}

// ---------------- CSR build ----------------
__global__ void count_kernel(const int* __restrict__ dst, int* __restrict__ cnt){
  int e = blockIdx.x*256 + threadIdx.x;
  if (e < EE) atomicAdd(&cnt[dst[e]], 1);
}

__global__ void scanA_kernel(const int* __restrict__ cnt, int* __restrict__ bsum){
  __shared__ int red[256];
  int t = threadIdx.x;
  red[t] = cnt[blockIdx.x*256 + t];
  __syncthreads();
  for (int s=128;s>0;s>>=1){
    if (t < s) red[t] += red[t+s];
    __syncthreads();
  }
  if (t == 0) bsum[blockIdx.x] = red[0];
}

__global__ void scanB_kernel(const int* __restrict__ bsum, int* __restrict__ boff){
  __shared__ int red[256];
  int t = threadIdx.x;
  int v = (t < 250) ? bsum[t] : 0;
  red[t] = v;
  __syncthreads();
  for (int d=1; d<256; d<<=1){
    int x = (t >= d) ? red[t-d] : 0;
    __syncthreads();
    red[t] += x;
    __syncthreads();
  }
  if (t < 250) boff[t] = red[t] - v;
  if (t == 249) boff[250] = red[t];
}

__global__ void scanC_kernel(const int* __restrict__ cnt, const int* __restrict__ boff,
                             int* __restrict__ off, int* __restrict__ cur){
  __shared__ int red[256];
  int t = threadIdx.x;
  int n = blockIdx.x*256 + t;
  int v = cnt[n];
  red[t] = v;
  __syncthreads();
  for (int d=1; d<256; d<<=1){
    int x = (t >= d) ? red[t-d] : 0;
    __syncthreads();
    red[t] += x;
    __syncthreads();
  }
  int excl = red[t] - v + boff[blockIdx.x];
  off[n] = excl; cur[n] = excl;
  if (n == NN-1) off[NN] = excl + v;
}

__global__ void fill_kernel(const int* __restrict__ src, const int* __restrict__ dst,
                            int* __restrict__ cur, int* __restrict__ csr){
  int e = blockIdx.x*256 + threadIdx.x;
  if (e < EE){
    int d = dst[e];
    int p = atomicAdd(&cur[d], 1);
    csr[p] = src[e];
  }
}

// ---------------- aggregation (layer >=1): big-grid standalone (TLP hides miss latency) ----
__global__ __launch_bounds__(256)
void agg128_kernel(const float* __restrict__ h, const int* __restrict__ off,
                   const int* __restrict__ csr, const int* __restrict__ cnt,
                   float* __restrict__ xin){
  const int nb = gridDim.x;
  const int per = nb >> 3;
  int bid = (blockIdx.x % 8)*per + (blockIdx.x >> 3);
  int w = (bid*256 + (int)threadIdx.x) >> 6;
  int lane = threadIdx.x & 63;
  if (w >= NN) return;
  const float* hn = h + (size_t)w*128;
  float a0 = hn[lane], a1 = hn[lane+64];
  float s0 = a0, s1 = a1;
  int e0 = off[w], e1 = off[w+1];
  int e = e0;
  for (; e + 4 <= e1; e += 4){
    int sA = csr[e], sB = csr[e+1], sC = csr[e+2], sD = csr[e+3];
    const float* pA = h + (size_t)sA*128;
    const float* pB = h + (size_t)sB*128;
    const float* pC = h + (size_t)sC*128;
    const float* pD = h + (size_t)sD*128;
    float a0A = pA[lane], a1A = pA[lane+64];
    float a0B = pB[lane], a1B = pB[lane+64];
    float a0C = pC[lane], a1C = pC[lane+64];
    float a0D = pD[lane], a1D = pD[lane+64];
    s0 += a0A; s1 += a1A;
    s0 += a0B; s1 += a1B;
    s0 += a0C; s1 += a1C;
    s0 += a0D; s1 += a1D;
  }
  for (; e < e1; ++e){
    int s = csr[e];
    const float* hs = h + (size_t)s*128;
    s0 += hs[lane]; s1 += hs[lane+64];
  }
  float di = 1.0f/(float)(cnt[w]+1);
  xin[(size_t)w*128 + lane]      = a0 + s0*di;
  xin[(size_t)w*128 + lane + 64] = a1 + s1*di;
}

// ---------------- layer-0: fused agg3 + z (K=3) with BN stats ----------------
__global__ __launch_bounds__(256)
void z0_kernel(const float* __restrict__ x, const int* __restrict__ off,
               const int* __restrict__ csr, const int* __restrict__ cnt,
               const float* __restrict__ W, const float* __restrict__ bias,
               float* __restrict__ z, float* __restrict__ stats){
  __shared__ float xr[192];
  __shared__ float ssum[128], ssq[128];
  int t = threadIdx.x;
  int row0 = blockIdx.x*64;
  if (t < 192){
    int nl = t/3, f = t - nl*3;
    int n = row0 + nl;
    float a = x[n*3+f];
    float s = a;
    int e1 = off[n+1];
    for (int e = off[n]; e < e1; ++e) s += x[csr[e]*3 + f];
    float di = 1.0f/(float)(cnt[n]+1);
    xr[t] = a + s*di;
  }
  if (t < 128){ ssum[t]=0.f; ssq[t]=0.f; }
  int f = t & 127, rg = t >> 7;
  float w0 = W[f], w1 = W[128+f], w2 = W[256+f], bb = bias[f];
  __syncthreads();
  float s = 0.f, q = 0.f;
  for (int i=0;i<32;i++){
    int r = rg*32 + i;
    float y = bb + xr[r*3]*w0 + xr[r*3+1]*w1 + xr[r*3+2]*w2;
    z[(size_t)(row0+r)*128 + f] = y;
    s += y; q += y*y;
  }
  atomicAdd(&ssum[f], s); atomicAdd(&ssq[f], q);
  __syncthreads();
  if (t < 128){ atomicAdd(&stats[t], ssum[t]); atomicAdd(&stats[128+t], ssq[t]); }
}

// ---------------- fp32 linear: 128 rows x 128 out per block, 8x8 micro-tile ----------------
// BN finalize folded into prologue. Do NOT grow the accumulator (16x8 spills: r8).
// Do NOT tighten bounds ((256,4) spills: r5). Do NOT keep a 64-reg acc live across
// transcendental-bearing tails (r16 scores spill).
template<int K, bool CATF, bool BNF, bool TANHF, bool STATSF, int POOLM>
__global__ __launch_bounds__(256, 2)
void linear_kernel(const float* X, const float* __restrict__ X2,
                   const float* __restrict__ W, const float* __restrict__ bias,
                   float* Y,
                   const float* __restrict__ statsIn, const float* __restrict__ gam,
                   const float* __restrict__ bet,
                   float* __restrict__ statsOut, float* __restrict__ pool){
  __shared__ __align__(16) float xs[32][LW];
  __shared__ __align__(16) float ws[32][LW];
  __shared__ float ssum[128], ssq[128];
  __shared__ __align__(16) float bnsc_s[128], bnsh_s[128];
  const int t = threadIdx.x;
  const int row0 = blockIdx.x*128;
  const int cg = t & 15, rg = t >> 4;
  const int c0 = cg*8, r0 = rg*8;
  const int skr0 = SKW(r0), skc0 = SKW(c0);
  float acc[8][8];
#pragma unroll
  for (int r=0;r<8;r++)
#pragma unroll
    for (int c=0;c<8;c++) acc[r][c]=0.f;
  if (STATSF && t < 128){ ssum[t]=0.f; ssq[t]=0.f; }
  if (BNF && t < 128){
    float mu  = statsIn[t]     * (1.0f/NN);
    float var = statsIn[128+t] * (1.0f/NN) - mu*mu;
    float rsv = rsqrtf(var + 1e-5f);
    float sc  = gam[t]*rsv;
    bnsc_s[t] = sc;
    bnsh_s[t] = bet[t] - mu*sc;
  }

  for (int kc=0; kc<K; kc+=32){
    __syncthreads();
#pragma unroll
    for (int i=0;i<4;i++){
      int task = t + 256*i;
      int n = task >> 3, k4 = task & 7;
      int gk = kc + k4*4;
      int row = row0 + n;
      float4 v;
      if (CATF){
        if (gk < 128) v = *(const float4*)(X  + (size_t)row*128 + gk);
        else          v = *(const float4*)(X2 + (size_t)(row/NPGc)*128 + (gk-128));
      } else {
        v = *(const float4*)(X + (size_t)row*K + gk);
      }
      if (BNF){
        float4 sc4 = *(const float4*)(bnsc_s + gk);
        float4 sh4 = *(const float4*)(bnsh_s + gk);
        v.x = fmaxf(0.f, v.x*sc4.x + sh4.x);
        v.y = fmaxf(0.f, v.y*sc4.y + sh4.y);
        v.z = fmaxf(0.f, v.z*sc4.z + sh4.z);
        v.w = fmaxf(0.f, v.w*sc4.w + sh4.w);
      }
      int ns = SKW(n);
      xs[k4*4+0][ns] = v.x; xs[k4*4+1][ns] = v.y;
      xs[k4*4+2][ns] = v.z; xs[k4*4+3][ns] = v.w;
    }
#pragma unroll
    for (int i=0;i<4;i++){
      int task = t + 256*i;
      int k = task >> 5, c4 = task & 31;
      float4 v = *(const float4*)(W + (size_t)(kc+k)*128 + c4*4);
      *(float4*)&ws[k][c4*4 + ((c4>>1)<<2)] = v;
    }
    __syncthreads();
#pragma unroll
    for (int k=0;k<32;k++){
      float4 xa = *(const float4*)&xs[k][skr0];
      float4 xb = *(const float4*)&xs[k][skr0+4];
      float4 wa = *(const float4*)&ws[k][skc0];
      float4 wb = *(const float4*)&ws[k][skc0+4];
      float xv[8] = {xa.x,xa.y,xa.z,xa.w,xb.x,xb.y,xb.z,xb.w};
      float wv[8] = {wa.x,wa.y,wa.z,wa.w,wb.x,wb.y,wb.z,wb.w};
#pragma unroll
      for (int r=0;r<8;r++)
#pragma unroll
        for (int c=0;c<8;c++)
          acc[r][c] += xv[r]*wv[c];
    }
  }
  float4 ba = *(const float4*)(bias + c0);
  float4 bb2 = *(const float4*)(bias + c0 + 4);
  float bv[8] = {ba.x,ba.y,ba.z,ba.w,bb2.x,bb2.y,bb2.z,bb2.w};
  float sc8[8], sq8[8];
#pragma unroll
  for (int c=0;c<8;c++){ sc8[c]=0.f; sq8[c]=0.f; }
#pragma unroll
  for (int r=0;r<8;r++){
    int n = row0 + r0 + r;
    float y[8];
#pragma unroll
    for (int c=0;c<8;c++){
      float v = acc[r][c] + bv[c];
      if (TANHF) v = fast_tanh(v);
      y[c] = v;
    }
    float4 y0; y0.x=y[0]; y0.y=y[1]; y0.z=y[2]; y0.w=y[3];
    float4 y1; y1.x=y[4]; y1.y=y[5]; y1.z=y[6]; y1.w=y[7];
    *(float4*)(Y + (size_t)n*128 + c0)     = y0;
    *(float4*)(Y + (size_t)n*128 + c0 + 4) = y1;
    if (POOLM == 1){
      *(float4*)(pool + (size_t)n*128 + c0)     = y0;
      *(float4*)(pool + (size_t)n*128 + c0 + 4) = y1;
    } else if (POOLM == 2){
      float4 p0 = *(const float4*)(pool + (size_t)n*128 + c0);
      float4 p1 = *(const float4*)(pool + (size_t)n*128 + c0 + 4);
      p0.x+=y[0]; p0.y+=y[1]; p0.z+=y[2]; p0.w+=y[3];
      p1.x+=y[4]; p1.y+=y[5]; p1.z+=y[6]; p1.w+=y[7];
      *(float4*)(pool + (size_t)n*128 + c0)     = p0;
      *(float4*)(pool + (size_t)n*128 + c0 + 4) = p1;
    }
    if (STATSF){
#pragma unroll
      for (int c=0;c<8;c++){ sc8[c]+=y[c]; sq8[c]+=y[c]*y[c]; }
    }
  }
  if (STATSF){
#pragma unroll
    for (int c=0;c<8;c++){
      atomicAdd(&ssum[c0+c], sc8[c]);
      atomicAdd(&ssq[c0+c],  sq8[c]);
    }
    __syncthreads();
    if (t < 128){
      atomicAdd(&statsOut[t],     ssum[t]);
      atomicAdd(&statsOut[128+t], ssq[t]);
    }
  }
}

// ---------------- graph pool (mean of node_pool per graph), 4-way row-parallel ----------------
__global__ __launch_bounds__(512)
void gpool_kernel(const float* __restrict__ pool, float* __restrict__ gpool){
  __shared__ float red[4][128];
  int b = blockIdx.x;
  int f = threadIdx.x & 127, part = threadIdx.x >> 7;
  const float* p = pool + (size_t)b*NPGc*128 + f;
  int rbeg = part*125, rend = rbeg + 125;
  float s = 0.f;
  for (int i=rbeg;i<rend;i++) s += p[(size_t)i*128];
  red[part][f] = s;
  __syncthreads();
  if (part == 0){
    float tot = ((red[0][f] + red[1][f]) + red[2][f]) + red[3][f];
    gpool[(size_t)b*128 + f] = tot * (1.0f/NPGc);
  }
}

// ---------------- triangle scores, 64x64 tile pairs (r15 proven: 197us, VGPR 80) ----------
// r16's 128x128 variant spilled (acc live across logf-bearing tail: 274MB scratch, 337us).
#define QCAP 1024
#define NPAIR 36

__global__ __launch_bounds__(256)
void scores_tri_kernel(const float* __restrict__ A, const unsigned char* __restrict__ mn8,
                       const unsigned char* __restrict__ mt8, float* __restrict__ partials){
  __shared__ __align__(16) float as[128][68];
  __shared__ __align__(16) float bs[32][68];
  __shared__ float qs[QCAP];
  __shared__ int   qi[QCAP];
  __shared__ int   qcnt;
  float* rm  = qs;
  float* rs_ = qs + 256;
  float* rv  = qs + 512;
  float* rsc = qs + 768;
  int*   ri  = qi;
  const int t = threadIdx.x;
  const int xcd = blockIdx.x & 7;
  const int within = blockIdx.x >> 3;
  const int b = xcd*16 + within/NPAIR;
  int pidx = within % NPAIR, tn = 0;
  while (pidx >= 8 - tn){ pidx -= 8 - tn; tn++; }
  const int tm = tn + pidx;
  const int pair = within % NPAIR;
  const bool diag = (tn == tm);
  const int n0 = tn*64, m0 = tm*64;
  const int cgc = t & 15, rgc = t >> 4;
  const int r0_ = rgc*4, c0 = cgc*4;
  const float* Ab = A + (size_t)b*NPGc*128;
  const unsigned gbase = (unsigned)b*250000u;
  if (t == 0) qcnt = 0;

#pragma unroll
  for (int i=0;i<32;i++){
    int idx = t + 256*i;
    int k = idx & 127, r = idx >> 7;
    int n = n0 + r;
    as[k][r] = (n < NPGc) ? Ab[(size_t)n*128 + k] : 0.f;
  }

  float acc[4][4];
#pragma unroll
  for (int i2=0;i2<4;i2++)
#pragma unroll
    for (int j=0;j<4;j++) acc[i2][j]=0.f;

  for (int kc=0;kc<4;kc++){
    __syncthreads();
#pragma unroll
    for (int i=0;i<8;i++){
      int idx = t + 256*i;
      int kk = idx & 31, c = idx >> 5;
      int m = m0 + c;
      bs[kk][c] = (m < NPGc) ? Ab[(size_t)m*128 + kc*32 + kk] : 0.f;
    }
    __syncthreads();
#pragma unroll
    for (int kk=0;kk<32;kk++){
      float4 av = *(const float4*)&as[kc*32+kk][r0_];
      float4 bv4 = *(const float4*)&bs[kk][c0];
      float a_[4] = {av.x,av.y,av.z,av.w};
      float b_[4] = {bv4.x,bv4.y,bv4.z,bv4.w};
#pragma unroll
      for (int i2=0;i2<4;i2++)
#pragma unroll
        for (int j=0;j<4;j++)
          acc[i2][j] += a_[i2]*b_[j];
    }
  }

  float mrun = -1e30f, srun = 0.f, bval = -FLT_MAX, bsc = 0.f;
  int bidx = 0x7FFFFFFF;
  const int mbase = m0 + c0;
  const bool colok = (mbase < NPGc);
#pragma unroll
  for (int i2=0;i2<4;i2++){
    int n = n0 + r0_ + i2;
    bool rowok = colok && (n < NPGc);
    bool fn[4] = {false,false,false,false};
    bool fm[4] = {false,false,false,false};
    if (rowok){
      size_t moff = (size_t)b*250000 + (size_t)n*500 + (size_t)mbase;
      uchar4 mk = *(const uchar4*)(mn8 + moff);
      fn[0]=mk.x!=0; fn[1]=mk.y!=0; fn[2]=mk.z!=0; fn[3]=mk.w!=0;
      uchar4 tk = *(const uchar4*)(mt8 + moff);
      fm[0]=tk.x!=0; fm[1]=tk.y!=0; fm[2]=tk.z!=0; fm[3]=tk.w!=0;
    }
    float cntj[4], sj[4];
    bool pn[4], pm[4];
#pragma unroll
    for (int j=0;j<4;j++){
      int m = mbase + j;
      bool mok = rowok && (m < NPGc);
      bool keep = mok && (!diag || m >= n);
      bool isde = (n == m);
      float cnt = 0.f; bool a1=false, a2=false;
      if (keep){
        if (isde){ cnt = fn[j] ? 1.f : 0.f; a1 = fn[j]; }
        else { cnt = (fn[j]?1.f:0.f) + (fm[j]?1.f:0.f); a1 = fn[j]; a2 = fm[j]; }
      }
      cntj[j]=cnt; pn[j]=a1; pm[j]=a2;
      sj[j] = (cnt > 0.f) ? acc[i2][j] : -1e30f;
    }
    float tmx = fmaxf(fmaxf(sj[0],sj[1]), fmaxf(sj[2],sj[3]));
    float nm = fmaxf(mrun, tmx);
    float add = 0.f;
#pragma unroll
    for (int j=0;j<4;j++) add += cntj[j]*__expf(sj[j] - nm);
    srun = srun*__expf(mrun - nm) + add;
    mrun = nm;
#pragma unroll
    for (int j=0;j<4;j++){
      int m = mbase + j;
      if (pn[j] || pm[j]){
        float s = acc[i2][j];
#pragma unroll
        for (int d=0;d<2;d++){
          bool doit = d ? pm[j] : pn[j];
          if (doit){
            int lidx = d ? (m*500 + n) : (n*500 + m);
            int slot = atomicAdd(&qcnt, 1);
            if (slot < QCAP){ qs[slot] = s; qi[slot] = lidx; }
            else {
              float g = gumbel_of(gbase + (unsigned)lidx);
              float val = s + g;
              if (val > bval || (val == bval && lidx < bidx)){ bval = val; bidx = lidx; bsc = s; }
            }
          }
        }
      }
    }
  }
  __syncthreads();
  int qn = qcnt; if (qn > QCAP) qn = QCAP;
  for (int i = t; i < qn; i += 256){
    float s = qs[i]; int idx = qi[i];
    float g = gumbel_of(gbase + (unsigned)idx);
    float val = s + g;
    if (val > bval || (val == bval && idx < bidx)){ bval = val; bidx = idx; bsc = s; }
  }
  __syncthreads();
  rm[t]=mrun; rs_[t]=srun; rv[t]=bval; ri[t]=bidx; rsc[t]=bsc;
  __syncthreads();
  for (int offr=128; offr>0; offr>>=1){
    if (t < offr){
      float m1 = rm[t], s1 = rs_[t];
      float m2 = rm[t+offr], s2 = rs_[t+offr];
      float M = fmaxf(m1, m2);
      float S = s1*expf(m1-M) + s2*expf(m2-M);
      rm[t] = M; rs_[t] = S;
      float v2 = rv[t+offr]; int i2_ = ri[t+offr];
      if (v2 > rv[t] || (v2 == rv[t] && i2_ < ri[t])){ rv[t]=v2; ri[t]=i2_; rsc[t]=rsc[t+offr]; }
    }
    __syncthreads();
  }
  if (t == 0){
    float* p = partials + ((size_t)b*NPAIR + pair)*8;
    p[0]=rm[0]; p[1]=rs_[0]; p[2]=rv[0]; p[3]=(float)ri[0]; p[4]=rsc[0];
  }
}

__global__ void finalize_kernel(const float* __restrict__ partials, float* __restrict__ out){
  int b = threadIdx.x;
  float M = -1e30f, S = 0.f, BV = -FLT_MAX, BS = 0.f;
  int BI = 0x7FFFFFFF;
  for (int tp=0; tp<NPAIR; tp++){
    const float* p = partials + ((size_t)b*NPAIR + tp)*8;
    float m = p[0], s = p[1], v = p[2]; int i = (int)p[3]; float sc2 = p[4];
    float nM = fmaxf(M, m);
    S = S*expf(M-nM) + s*expf(m-nM);
    M = nM;
    if (v > BV || (v == BV && i < BI)){ BV = v; BI = i; BS = sc2; }
  }
  out[b]      = (float)BI;
  out[BB + b] = BS - (M + logf(S));
}

// ---------------- host launch ----------------
extern "C" void kernel_launch(void* const* d_in, const int* in_sizes, int n_in,
                              void* d_out, int out_size, void* d_ws, size_t ws_size,
                              hipStream_t stream){
  const float* x        = (const float*)d_in[0];
  const int*   eidx     = (const int*)d_in[1];
  const void*  maskp    = d_in[3];
  const float* gin_W1_0 = (const float*)d_in[4];
  const float* gin_b1_0 = (const float*)d_in[5];
  const float* gin_g_0  = (const float*)d_in[6];
  const float* gin_be_0 = (const float*)d_in[7];
  const float* gin_W2_0 = (const float*)d_in[8];
  const float* gin_b2_0 = (const float*)d_in[9];
  const float* gin_W1   = (const float*)d_in[10];
  const float* gin_b1   = (const float*)d_in[11];
  const float* gin_g    = (const float*)d_in[12];
  const float* gin_be   = (const float*)d_in[13];
  const float* gin_W2   = (const float*)d_in[14];
  const float* gin_b2   = (const float*)d_in[15];
  const float* pol_W1_0 = (const float*)d_in[16];
  const float* pol_b1_0 = (const float*)d_in[17];
  const float* pol_W2_0 = (const float*)d_in[18];
  const float* pol_b2_0 = (const float*)d_in[19];
  const float* pol_W1   = (const float*)d_in[20];
  const float* pol_b1   = (const float*)d_in[21];
  const float* pol_W2   = (const float*)d_in[22];
  const float* pol_b2   = (const float*)d_in[23];
  float* out = (float*)d_out;

  char* p = (char*)d_ws;
  auto carve = [&](size_t bytes) -> void* {
    void* r = (void*)p; p += (bytes + 255) & ~(size_t)255; return r;
  };
  float* hbuf  = (float*)carve((size_t)NN*128*4);
  float* xin   = (float*)carve((size_t)NN*128*4);
  float* pool  = (float*)carve((size_t)NN*128*4);
  float* gpool = (float*)carve((size_t)BB*128*4);
  float* stats = (float*)carve(4*256*4);
  float* partials = (float*)carve((size_t)BB*NPAIR*8*4);
  int* cnt  = (int*)carve((size_t)NN*4);
  int* off  = (int*)carve((size_t)(NN+1)*4);
  int* cur  = (int*)carve((size_t)NN*4);
  int* csr  = (int*)carve((size_t)EE*4);
  int* bsum = (int*)carve(256*4);
  int* boff = (int*)carve(256*4);
  unsigned char* mn8 = (unsigned char*)carve((size_t)BB*250000);
  unsigned char* mt8 = (unsigned char*)carve((size_t)BB*250000);

  const int* srcp = eidx;
  const int* dstp = eidx + EE;

  {
    dim3 mg(64, BB);
    maskprep_kernel<<<mg, 256, 0, stream>>>((const unsigned char*)maskp, (const int*)maskp,
                                            mn8, mt8);
  }

  hipMemsetAsync(cnt, 0, (size_t)NN*4, stream);
  hipMemsetAsync(stats, 0, 4*256*4, stream);
  count_kernel<<<(EE+255)/256, 256, 0, stream>>>(dstp, cnt);
  scanA_kernel<<<NN/256, 256, 0, stream>>>(cnt, bsum);
  scanB_kernel<<<1, 256, 0, stream>>>(bsum, boff);
  scanC_kernel<<<NN/256, 256, 0, stream>>>(cnt, boff, off, cur);
  fill_kernel<<<(EE+255)/256, 256, 0, stream>>>(srcp, dstp, cur, csr);

  // GIN layer 0
  z0_kernel<<<NN/64, 256, 0, stream>>>(x, off, csr, cnt, gin_W1_0, gin_b1_0, xin, stats);
  linear_kernel<128,false,true,false,false,1><<<NN/128, 256, 0, stream>>>(
      xin, nullptr, gin_W2_0, gin_b2_0, hbuf, stats, gin_g_0, gin_be_0, nullptr, pool);

  // GIN layers 1..3
  for (int l=0; l<3; l++){
    float* st = stats + (l+1)*256;
    agg128_kernel<<<NN/4, 256, 0, stream>>>(hbuf, off, csr, cnt, xin);
    linear_kernel<128,false,false,false,true,0><<<NN/128, 256, 0, stream>>>(
        xin, nullptr, gin_W1 + (size_t)l*16384, gin_b1 + l*128, xin,
        nullptr, nullptr, nullptr, st, nullptr);
    linear_kernel<128,false,true,false,false,2><<<NN/128, 256, 0, stream>>>(
        xin, nullptr, gin_W2 + (size_t)l*16384, gin_b2 + l*128, hbuf,
        st, gin_g + l*128, gin_be + l*128, nullptr, pool);
  }

  // policy MLP
  gpool_kernel<<<BB, 512, 0, stream>>>(pool, gpool);
  linear_kernel<256,true,false,true,false,0><<<NN/128, 256, 0, stream>>>(
      pool, gpool, pol_W1_0, pol_b1_0, hbuf, nullptr, nullptr, nullptr, nullptr, nullptr);
  linear_kernel<128,false,false,false,false,0><<<NN/128, 256, 0, stream>>>(
      hbuf, nullptr, pol_W2_0, pol_b2_0, xin, nullptr, nullptr, nullptr, nullptr, nullptr);
  linear_kernel<128,false,false,true,false,0><<<NN/128, 256, 0, stream>>>(
      xin, nullptr, pol_W1, pol_b1, hbuf, nullptr, nullptr, nullptr, nullptr, nullptr);
  linear_kernel<128,false,false,false,false,0><<<NN/128, 256, 0, stream>>>(
      hbuf, nullptr, pol_W2, pol_b2, xin, nullptr, nullptr, nullptr, nullptr, nullptr);
  linear_kernel<128,false,false,true,false,0><<<NN/128, 256, 0, stream>>>(
      xin, nullptr, pol_W1 + 16384, pol_b1 + 128, hbuf, nullptr, nullptr, nullptr, nullptr, nullptr);
  linear_kernel<128,false,false,false,false,0><<<NN/128, 256, 0, stream>>>(
      hbuf, nullptr, pol_W2 + 16384, pol_b2 + 128, xin, nullptr, nullptr, nullptr, nullptr, nullptr);

  // scores + sampling (64x64 triangle tile pairs, XCD-pinned)
  scores_tri_kernel<<<8*16*NPAIR, 256, 0, stream>>>(xin, mn8, mt8, partials);
  finalize_kernel<<<1, BB, 0, stream>>>(partials, out);
}